// Round 1
// baseline (41.784 us; speedup 1.0000x reference)
//
#include <hip/hip_runtime.h>

#define DELAY   4410
#define NPAIR   2205      // DELAY/2, float2 lanes
#define NCHUNK  6000
#define FB      0.5f
#define TCH     120       // chunks per block (6000 % 120 == 0)
#define KLOOK   32        // warm-up lookback chunks: 0.5^32 ~ 2e-10 -> exact to f32
#define THREADS 256

__global__ __launch_bounds__(THREADS)
void ReverbModel_67508295958534_kernel(const float* __restrict__ x,
                                       float* __restrict__ y) {
    int p = blockIdx.x * THREADS + threadIdx.x;   // lane-pair index
    if (p >= NPAIR) return;
    const int c0 = blockIdx.y * TCH;

    const float2* __restrict__ x2 = (const float2*)x;
    float2* __restrict__ y2 = (float2*)y;

    float cy0 = 0.0f, cy1 = 0.0f;   // carry = y[c0-1] (approx via truncated history)

    // Warm-up: run the recurrence over the previous KLOOK chunks starting
    // from zero. Truncation error <= 0.5^KLOOK * |y| ~ 2e-9 (negligible).
    int cstart = c0 - KLOOK;
    if (cstart < 0) cstart = 0;
    #pragma unroll 8
    for (int c = cstart; c < c0; ++c) {
        float2 v = x2[(size_t)c * NPAIR + p];
        cy0 = v.x + FB * cy0;
        cy1 = v.y + FB * cy1;
    }

    // Main streamed scan over this block's chunk range.
    int cend = c0 + TCH;
    if (cend > NCHUNK) cend = NCHUNK;
    #pragma unroll 8
    for (int c = c0; c < cend; ++c) {
        float2 v = x2[(size_t)c * NPAIR + p];
        cy0 = v.x + FB * cy0;
        cy1 = v.y + FB * cy1;
        y2[(size_t)c * NPAIR + p] = make_float2(cy0, cy1);
    }
}

extern "C" void kernel_launch(void* const* d_in, const int* in_sizes, int n_in,
                              void* d_out, int out_size, void* d_ws, size_t ws_size,
                              hipStream_t stream) {
    const float* x = (const float*)d_in[0];
    float* y = (float*)d_out;

    dim3 grid((NPAIR + THREADS - 1) / THREADS,   // 9 lane-blocks
              NCHUNK / TCH);                     // 50 chunk-blocks
    dim3 block(THREADS);
    ReverbModel_67508295958534_kernel<<<grid, block, 0, stream>>>(x, y);
}